// Round 8
// baseline (166.181 us; speedup 1.0000x reference)
//
#include <hip/hip_runtime.h>
#include <stdint.h>

// Problem constants: N=16384, M=1024, D=1024, fp32 in/out
#define NN 16384
#define MM 1024
#define DD 1024

typedef __attribute__((ext_vector_type(4)))  int   int4v;
typedef __attribute__((ext_vector_type(8)))  int   int8v;   // 32 fp8 = one MFMA A/B frag
typedef __attribute__((ext_vector_type(4)))  float f4;
typedef __attribute__((ext_vector_type(16))) float f16v;    // 32x32 MFMA C/D frag

// ---------------------------------------------------------------------------
// Fragment-tiled global layout (round 8): operand byte for (row, k) lives at
//   addr(row,k) = (row>>5)*32768 + (k>>6)*2048 + ((row&31) + 32*((k>>5)&1))*32 + (k&31)
// i.e. [row-tile][k-step 64][lane][32B], matching mfma_32x32x64 A/B fragments:
// lane&31 = row, lane>>5 = k-half, bytes = 32 consecutive k. The GEMM loads
// operands straight from global into VGPRs -- NO LDS, NO barriers. Any hidden
// within-64 k-permutation cancels (A and B share the mapping); C/D layout is
// the m74/m101-verified one. We control all producers, so everything (x8, c8,
// n8 from prologue; dens8 from stage-1 epilogue) is written in this layout.
// ---------------------------------------------------------------------------
__device__ __forceinline__ size_t frag_addr(int row, int k) {
    return (size_t)(row >> 5) * 32768 + (size_t)((k >> 6)) * 2048
         + (size_t)((row & 31) + 32 * ((k >> 5) & 1)) * 32 + (k & 31);
}

// pack 4 fp32 -> 4 OCP e4m3 bytes in a dword (HW RNE; byte order a,b,c,d)
__device__ __forceinline__ uint32_t pk4fp8(float a, float b, float c, float d) {
    uint32_t lo = __builtin_amdgcn_cvt_pk_fp8_f32(a, b, 0, false);
    return __builtin_amdgcn_cvt_pk_fp8_f32(c, d, lo, true);
}

// ---- fused row squared-norms + fp32->fp8 fragment-layout convert ----
__global__ __launch_bounds__(256)
void rowsq_cvt8_all(const float* __restrict__ x, const float* __restrict__ cen,
                    float* __restrict__ xsq, float* __restrict__ csq,
                    uint8_t* __restrict__ x8, uint8_t* __restrict__ c8) {
    int row  = (blockIdx.x * 256 + threadIdx.x) >> 6;
    int lane = threadIdx.x & 63;
    const float* src; float* sq; uint8_t* fb; int r;
    if (row < NN) { r = row;      src = x   + (size_t)r * DD; sq = xsq + r; fb = x8; }
    else          { r = row - NN; src = cen + (size_t)r * DD; sq = csq + r; fb = c8; }
    const f4* p = (const f4*)src;
    float s = 0.f;
    for (int i = lane; i < DD / 4; i += 64) {
        f4 v = p[i];
        s = fmaf(v.x, v.x, s); s = fmaf(v.y, v.y, s);
        s = fmaf(v.z, v.z, s); s = fmaf(v.w, v.w, s);
        *(uint32_t*)(fb + frag_addr(r, 4 * i)) = pk4fp8(v.x, v.y, v.z, v.w);
    }
#pragma unroll
    for (int off = 32; off > 0; off >>= 1) s += __shfl_down(s, off);
    if (lane == 0) *sq = s;
}

// ---- norm fp32 [k][c] -> fp8 fragment layout (col=c, k) ----
__global__ __launch_bounds__(256)
void trcvt8(const float* __restrict__ in, uint8_t* __restrict__ out) {
    __shared__ float t[32][33];
    int tx = threadIdx.x & 31, ty = threadIdx.x >> 5;  // 32 x 8
    int k0 = blockIdx.y * 32, c0 = blockIdx.x * 32;
#pragma unroll
    for (int i = 0; i < 32; i += 8)    // t[k-k0][c-c0]
        t[ty + i][tx] = in[(size_t)(k0 + ty + i) * MM + c0 + tx];
    __syncthreads();
    int c  = threadIdx.x >> 3;         // 0..31 (local col)
    int kg = (threadIdx.x & 7) * 4;    // 0,4,...,28 (local k group)
    uint32_t u = pk4fp8(t[kg + 0][c], t[kg + 1][c], t[kg + 2][c], t[kg + 3][c]);
    *(uint32_t*)(out + frag_addr(c0 + c, k0 + kg)) = u;
}

// ---- LDS-free MX-fp8 MFMA GEMM, 128x128 tile, 4 waves (2x2), 64x64/wave ----
// Per 64-deep k-step: 8 global 32B fragment loads + 8 mfma_scale_32x32x64.
// Register-double-buffered (load step s+1 while step s computes); zero
// barriers -- loads stay in flight across the whole K loop (AITER-style).
// A: fragment layout (rows of x / dens). B: fragment layout (cols = centers /
// norm columns). EXP_EPI: dens8 = exp(-g*(xsq+csq-2acc)) written in fragment
// layout for stage 2's A; else C(fp32 row-major) = acc.
template<bool EXP_EPI>
__global__ __launch_bounds__(256)
void mfma_gemm_fp8(const uint8_t* __restrict__ A, const uint8_t* __restrict__ B,
                   void* __restrict__ Cv, const float* __restrict__ xsq,
                   const float* __restrict__ csq, const float* __restrict__ gamma_p)
{
    constexpr int NC = 1024, NSTEP = 16;   // K = 1024 = 16 x 64
    const int tid  = threadIdx.x;
    const int lane = tid & 63;
    const int wave = tid >> 6;
    const int l31  = lane & 31;
    const int kh   = lane >> 5;
    const int wm   = (wave >> 1) * 64;
    const int wn   = (wave & 1) * 64;

    // XCD swizzle (round-3 verified: FETCH 264->33 MB): xcd = bid&7; each XCD
    // owns 16 consecutive row-panels; col-blocks of a panel back-to-back.
    const int bid  = blockIdx.x;           // 0..1023
    const int xcd  = bid & 7;
    const int slot = bid >> 3;
    const int bcol = (slot & 7) * 128;
    const int brow = ((xcd << 4) | (slot >> 3)) * 128;

    // fragment base pointers: row tiles (brow+wm)/32 + mi, col tiles likewise
    const uint8_t* aP[2], * bP[2];
#pragma unroll
    for (int i = 0; i < 2; ++i) {
        aP[i] = A + (size_t)(((brow + wm) >> 5) + i) * 32768 + (size_t)lane * 32;
        bP[i] = B + (size_t)(((bcol + wn) >> 5) + i) * 32768 + (size_t)lane * 32;
    }

    const float gam = EXP_EPI ? gamma_p[0] : 0.f;   // hoisted loads
    float cs[2];
    if constexpr (EXP_EPI) {
        cs[0] = csq[bcol + wn + l31];
        cs[1] = csq[bcol + wn + 32 + l31];
    }

    f16v acc[2][2];
#pragma unroll
    for (int mi = 0; mi < 2; ++mi)
#pragma unroll
        for (int ni = 0; ni < 2; ++ni)
#pragma unroll
            for (int r = 0; r < 16; ++r) acc[mi][ni][r] = 0.f;

    int8v a[2][2], b[2][2];                 // [buf][tile]
#pragma unroll
    for (int i = 0; i < 2; ++i) {           // prefetch step 0
        a[0][i] = *(const int8v*)(aP[i]);
        b[0][i] = *(const int8v*)(bP[i]);
    }
#pragma unroll
    for (int s = 0; s < NSTEP; ++s) {
        const int cb = s & 1;
        if (s + 1 < NSTEP) {                // loads fly during MFMAs below
            const size_t o = (size_t)(s + 1) * 2048;
#pragma unroll
            for (int i = 0; i < 2; ++i) {
                a[cb ^ 1][i] = *(const int8v*)(aP[i] + o);
                b[cb ^ 1][i] = *(const int8v*)(bP[i] + o);
            }
        }
#pragma unroll
        for (int mi = 0; mi < 2; ++mi)
#pragma unroll
            for (int ni = 0; ni < 2; ++ni)
                acc[mi][ni] = __builtin_amdgcn_mfma_scale_f32_32x32x64_f8f6f4(
                    a[cb][mi], b[cb][ni], acc[mi][ni],
                    0, 0, 0, 0x7F7F7F7F, 0, 0x7F7F7F7F);  // fp8, scales = 1.0
    }

    // C/D layout (32x32, m74/m101): col = lane&31, row = (reg&3)+8*(reg>>2)+4*kh
    if constexpr (EXP_EPI) {
        uint8_t* C = (uint8_t*)Cv;          // dens8 in fragment layout (stage-2 A)
#pragma unroll
        for (int mi = 0; mi < 2; ++mi)
#pragma unroll
            for (int r = 0; r < 16; ++r) {
                int rl  = (r & 3) + 8 * (r >> 2) + 4 * kh;
                int row = brow + wm + mi * 32 + rl;
                float xs = xsq[row];
#pragma unroll
                for (int ni = 0; ni < 2; ++ni) {
                    int col = bcol + wn + ni * 32 + l31;
                    float sq = xs + cs[ni] - 2.0f * acc[mi][ni][r];
                    float d = __expf(-gam * sq);   // underflows to 0 (sq ~>1500)
                    C[frag_addr(row, col)] =
                        (uint8_t)(__builtin_amdgcn_cvt_pk_fp8_f32(d, d, 0, false) & 0xFF);
                }
            }
    } else {
        float* C = (float*)Cv;              // fp32 row-major output
#pragma unroll
        for (int mi = 0; mi < 2; ++mi)
#pragma unroll
            for (int r = 0; r < 16; ++r) {
                int rl  = (r & 3) + 8 * (r >> 2) + 4 * kh;
                int row = brow + wm + mi * 32 + rl;
#pragma unroll
                for (int ni = 0; ni < 2; ++ni)
                    C[(size_t)row * NC + bcol + wn + ni * 32 + l31] = acc[mi][ni][r];
            }
    }
}

extern "C" void kernel_launch(void* const* d_in, const int* in_sizes, int n_in,
                              void* d_out, int out_size, void* d_ws, size_t ws_size,
                              hipStream_t stream) {
    const float* inputs  = (const float*)d_in[0];   // [N, D]
    const float* centers = (const float*)d_in[1];   // [M, D]
    const float* gamma   = (const float*)d_in[2];   // [1]
    const float* norm    = (const float*)d_in[3];   // [M, M]
    float* out = (float*)d_out;                     // [N, M]

    // ws layout: xsq 64K | csq 4K | c8 1M | n8 1M | dens8 16M  (~18.1 MiB)
    char* w = (char*)d_ws;
    float*   xsq   = (float*)w;
    float*   csq   = (float*)(w + 65536);
    uint8_t* c8    = (uint8_t*)(w + 69632);
    uint8_t* n8    = (uint8_t*)(w + 69632 + (1u << 20));
    uint8_t* dens8 = (uint8_t*)(w + 69632 + (2u << 20));
    // x8 (16 MB, fragment layout) parked in d_out: dead before stage 2 writes.
    uint8_t* x8    = (uint8_t*)d_out;

    rowsq_cvt8_all<<<(NN + MM) / 4, 256, 0, stream>>>(
        inputs, centers, xsq, csq, x8, c8);
    trcvt8<<<dim3(32, 32), 256, 0, stream>>>(norm, n8);

    // stage 1: dens = exp(-g * (xsq + csq - 2 * x @ centers^T)), fragment-fp8 out
    mfma_gemm_fp8<true><<<1024, 256, 0, stream>>>(x8, c8, dens8, xsq, csq, gamma);
    // stage 2: out = dens @ norm, fp32 out
    mfma_gemm_fp8<false><<<1024, 256, 0, stream>>>(dens8, n8, out, nullptr, nullptr, nullptr);
}